// Round 8
// baseline (259.654 us; speedup 1.0000x reference)
//
#include <hip/hip_runtime.h>
#include <math.h>

#define L_SEQ   2048
#define BATCH_N 8
#define H_DIM   1024
#define P_DIM   512
#define M_DIM   (BATCH_N * L_SEQ)   // 16384
#define N2      1024                // packed complex width (re | im)
#define NC      32                  // scan chunks
#define T_CHUNK 64                  // L_SEQ / NC

typedef __attribute__((ext_vector_type(8))) __bf16 bf16x8;
typedef __attribute__((ext_vector_type(4))) float f32x4;

__device__ __forceinline__ unsigned f2bf_bits(float f) {
    unsigned u = __builtin_bit_cast(unsigned, f);
    return (u + 0x7fffu + ((u >> 16) & 1u)) >> 16;   // RNE
}
__device__ __forceinline__ float bf_lo(unsigned v) {
    return __builtin_bit_cast(float, v << 16);
}
__device__ __forceinline__ float bf_hi(unsigned v) {
    return __builtin_bit_cast(float, v & 0xffff0000u);
}
__device__ __forceinline__ float bf2f(unsigned short u) {
    return __builtin_bit_cast(float, (unsigned)u << 16);
}

#define ASYNC_COPY16(gsrc, ldst)                                            \
    __builtin_amdgcn_global_load_lds(                                       \
        (__attribute__((address_space(1))) void*)(gsrc),                    \
        (__attribute__((address_space(3))) void*)(ldst), 16, 0, 0)

// ---------------------------------------------------------------------------
// prep: fused setup_lam + build_W + convert_sig (verified round 7) + zeroing
// of the scan's per-batch barrier counters (cnt[8]).
//   blocks [0, 16384)        : convert signal f32 -> bf16 (4 elem/thread)
//   blocks [16384, 20480)    : build W1/W2; W1-half recomputes lam inline
//   blocks [20480, 20482)    : write lam_re/lam_im buffer + zero cnt
// lam buffer: [lam_re(512) | lam_im(512)]  (fp32)
// ---------------------------------------------------------------------------
#define NB_CONV 16384
#define NB_W    4096

__global__ __launch_bounds__(256) void prep(
    const float* __restrict__ signal, unsigned short* __restrict__ sigbf,
    const float* __restrict__ Lre_in, const float* __restrict__ Lim_in,
    const float* __restrict__ log_step,
    const float* __restrict__ B, const float* __restrict__ C,
    unsigned short* __restrict__ W1, unsigned short* __restrict__ W2,
    float* __restrict__ lam, int* __restrict__ cnt)
{
    int bid = blockIdx.x;
    if (bid < NB_CONV) {
        size_t i = ((size_t)bid * 256 + threadIdx.x) * 4;
        float4 v = *(const float4*)(signal + i);
        ushort4 o;
        o.x = (unsigned short)f2bf_bits(v.x);
        o.y = (unsigned short)f2bf_bits(v.y);
        o.z = (unsigned short)f2bf_bits(v.z);
        o.w = (unsigned short)f2bf_bits(v.w);
        *(ushort4*)(sigbf + i) = o;
    } else if (bid < NB_CONV + NB_W) {
        int idx = (bid - NB_CONV) * 256 + threadIdx.x;
        if (idx < P_DIM * H_DIM) {                   // W1 half: idx over P*H
            int p = idx >> 10;
            int h = idx & (H_DIM - 1);
            float step = expf(log_step[p]);
            float c = Lre_in[p];
            float d = Lim_in[p];
            float mag = expf(c * step);
            float ang = d * step;
            float lr = mag * cosf(ang);
            float li = mag * sinf(ang);
            float a = lr - 1.0f, bb = li;
            float inv = 1.0f / (c * c + d * d);
            float gre = (a * c + bb * d) * inv;
            float gim = (bb * c - a * d) * inv;
            float bre = B[(size_t)idx * 2];
            float bim = B[(size_t)idx * 2 + 1];
            W1[(size_t)p * H_DIM + h]           = (unsigned short)f2bf_bits(gre * bre - gim * bim);
            W1[(size_t)(P_DIM + p) * H_DIM + h] = (unsigned short)f2bf_bits(gre * bim + gim * bre);
        } else {                                     // W2 half: idx over H*P
            int j = idx - P_DIM * H_DIM;
            int h = j >> 9;
            int p = j & (P_DIM - 1);
            float cre = C[(size_t)j * 2];
            float cim = C[(size_t)j * 2 + 1];
            W2[(size_t)h * N2 + p]         = (unsigned short)f2bf_bits( 2.0f * cre);
            W2[(size_t)h * N2 + P_DIM + p] = (unsigned short)f2bf_bits(-2.0f * cim);
        }
    } else {
        int p = (bid - (NB_CONV + NB_W)) * 256 + threadIdx.x;
        if (p < P_DIM) {
            float step = expf(log_step[p]);
            float c = Lre_in[p];
            float d = Lim_in[p];
            float mag = expf(c * step);
            float ang = d * step;
            lam[p]         = mag * cosf(ang);
            lam[P_DIM + p] = mag * sinf(ang);
        }
        if (bid == NB_CONV + NB_W && threadIdx.x < BATCH_N)
            cnt[threadIdx.x] = 0;    // scan barrier counters (re-zeroed each run)
    }
}

// ---------------------------------------------------------------------------
// bf16 MFMA GEMM (round-0 verified structure -- best measured: 44 us).
// Out[m][n] = sum_k A[m][k]*W[n][k].
// A: M x K bf16 row-major, W: N x K bf16 row-major (K = 1024).
// Block tile 128(m) x 128(n), BK=64, LDS 32 KB. 256 thr = 4 waves in 2x2;
// wave tile 64x64 = 4x4 frags of 16x16x32 MFMA (verified layout).
// Grid 1024, __launch_bounds__(256,4) -> 4 blocks/CU (16 waves): barrier
// drains overlap across blocks.
// LDS k-slot swizzle: slot' = (slot + (row>>1)) & 7, via rotating the
// *global* source quad per lane at stage time. NOTE (rounds 1-3 A/B):
// SQ_LDS_BANK_CONFLICT is a constant 4 cyc per ds_read_b128 under ANY
// swizzle -- structural wave64-b128 cost, not mis-banking. Do not chase.
// XCD swizzle: XCD x owns m-blocks [16x, 16x+16); 8 n-blocks consecutive.
// MODE 0: bf16 out via LDS-transposed coalesced 16B stores (2 phases).
// MODE 1: f32 out, + D[col]*bf2f(SigBf[row][col]) fused.
// ---------------------------------------------------------------------------
template <int MODE>
__global__ __launch_bounds__(256, 4) void gemm_mfma(
    const unsigned short* __restrict__ A,
    const unsigned short* __restrict__ W,
    void* __restrict__ Out, int K,
    const float* __restrict__ Dvec, const unsigned short* __restrict__ SigBf)
{
    __shared__ unsigned short smem[128 * 64 * 2];   // As 16K | Ws 16K
    unsigned short* As = smem;
    unsigned short* Ws = smem + 128 * 64;

    const int tid  = threadIdx.x;
    const int lane = tid & 63;
    const int wid  = tid >> 6;
    const int wm   = wid >> 1;     // 0..1
    const int wn   = wid & 1;      // 0..1

    // XCD swizzle: 128 m-blocks x 8 n-blocks, XCD x -> m-blocks [16x,16x+16)
    const int id  = blockIdx.x;
    const int xcd = id & 7;
    const int j   = id >> 3;              // 0..127
    const int mb  = xcd * 16 + (j >> 3);  // m-block (128 rows)
    const int nb  = j & 7;                // n-block (128 cols)
    const int m0 = mb * 128;
    const int n0 = nb * 128;

    // --- staging geometry (swizzled) --------------------------------------
    const int srow = tid >> 3;                                  // 0..31
    const int qg   = ((tid & 7) - ((tid >> 4) & 7)) & 7;        // const/lane
    const unsigned short* Abase = A + (size_t)(m0 + srow) * K + qg * 8;
    const unsigned short* Wbase = W + (size_t)(n0 + srow) * K + qg * 8;

    const int fr = lane & 15;        // m-row / n-col within 16
    const int fq = (lane >> 4) & 3;  // k-quad within 32
    const int sw = fr >> 1;          // swizzle rotation for this lane

    f32x4 acc[4][4] = {};

    for (int k0 = 0; k0 < K; k0 += 64) {
        __syncthreads();
        #pragma unroll
        for (int i = 0; i < 4; ++i)      // A: 1024 chunks (128 rows x 8 slots)
            ASYNC_COPY16(Abase + (size_t)(i * 32) * K + k0,
                         As + (size_t)(i * 256 + wid * 64) * 8);
        #pragma unroll
        for (int i = 0; i < 4; ++i)      // W: 1024 chunks
            ASYNC_COPY16(Wbase + (size_t)(i * 32) * K + k0,
                         Ws + (size_t)(i * 256 + wid * 64) * 8);
        __syncthreads();

        #pragma unroll
        for (int kk = 0; kk < 2; ++kk) {
            bf16x8 af[4], wf[4];
            #pragma unroll
            for (int mi = 0; mi < 4; ++mi) {
                int row = wm * 64 + mi * 16 + fr;
                int sl  = (kk * 4 + fq + sw) & 7;
                af[mi] = *(const bf16x8*)&As[(size_t)row * 64 + sl * 8];
            }
            #pragma unroll
            for (int ni = 0; ni < 4; ++ni) {
                int row = wn * 64 + ni * 16 + fr;
                int sl  = (kk * 4 + fq + sw) & 7;
                wf[ni] = *(const bf16x8*)&Ws[(size_t)row * 64 + sl * 8];
            }
            #pragma unroll
            for (int mi = 0; mi < 4; ++mi)
                #pragma unroll
                for (int ni = 0; ni < 4; ++ni)
                    acc[mi][ni] = __builtin_amdgcn_mfma_f32_16x16x32_bf16(
                        af[mi], wf[ni], acc[mi][ni], 0, 0, 0);
        }
    }

    // C/D layout (m89): col = lane&15, row = (lane>>4)*4 + reg
    if (MODE == 0) {
        // bf16 out: transpose through LDS (two 64x128 half-tiles, 16 KB)
        unsigned short* T = smem;
        #pragma unroll
        for (int h = 0; h < 2; ++h) {
            __syncthreads();       // prior LDS readers done
            if (wm == h) {
                #pragma unroll
                for (int mi = 0; mi < 4; ++mi)
                    #pragma unroll
                    for (int ni = 0; ni < 4; ++ni)
                        #pragma unroll
                        for (int r = 0; r < 4; ++r) {
                            int lrow = mi * 16 + fq * 4 + r;      // 0..63
                            int lcol = wn * 64 + ni * 16 + fr;    // 0..127
                            T[lrow * 128 + lcol] =
                                (unsigned short)f2bf_bits(acc[mi][ni][r]);
                        }
            }
            __syncthreads();
            // 64 rows x 128 cols = 1024 chunks of 8 ushorts (16 B)
            #pragma unroll
            for (int jj = 0; jj < 4; ++jj) {
                int chunk = jj * 256 + tid;        // 0..1023
                int row = chunk >> 4;              // 0..63
                int co  = (chunk & 15) * 8;        // 0..120
                *(ulonglong2*)((unsigned short*)Out +
                    (size_t)(m0 + h * 64 + row) * 1024 + n0 + co) =
                    *(const ulonglong2*)&T[row * 128 + co];
            }
        }
    } else {
        float Dl[4];
        #pragma unroll
        for (int ni = 0; ni < 4; ++ni)
            Dl[ni] = Dvec[n0 + wn * 64 + ni * 16 + fr];
        #pragma unroll
        for (int mi = 0; mi < 4; ++mi) {
            #pragma unroll
            for (int ni = 0; ni < 4; ++ni) {
                #pragma unroll
                for (int r = 0; r < 4; ++r) {
                    int row = m0 + wm * 64 + mi * 16 + fq * 4 + r;
                    int col = n0 + wn * 64 + ni * 16 + fr;
                    float v = acc[mi][ni][r];
                    v = fmaf(Dl[ni], bf2f(SigBf[(size_t)row * 1024 + col]), v);
                    ((float*)Out)[(size_t)row * 1024 + col] = v;
                }
            }
        }
    }
}

// ---------------------------------------------------------------------------
// Fused scan, PLAIN launch (no cooperative API -- round 6's hang was most
// likely hipLaunchCooperativeKernel x graph-capture).
// Grid (8,32) = 256 blocks x 256 thr = 1 block/CU -> all blocks co-resident.
// Phase A = verified scan_sums body; then per-batch atomic-counter barrier
// (threadfence + atomicAdd; spin on cnt[b] >= NC -- ">=" so stale counters
// from rocprof single-dispatch replays fall through instead of deadlocking;
// prep re-zeros cnt each graph run); then phase B = verified Horner-carry +
// apply body. Phase B's Bu re-read hits the same XCD's L2 (32 blk/XCD x
// 128 KB = 4 MB). Saves one launch + HBM->L2 on the second Bu pass.
// ---------------------------------------------------------------------------
__global__ __launch_bounds__(256) void scan_fused(
    unsigned short* __restrict__ Bu, const float* __restrict__ lam,
    float* __restrict__ S, int* __restrict__ cnt,
    float* __restrict__ out_state, int interleaved)
{
    int b = blockIdx.x, c = blockIdx.y, t = threadIdx.x;
    int p0 = 2 * t, p1 = 2 * t + 1;
    float lr0 = lam[p0], li0 = lam[P_DIM + p0];
    float lr1 = lam[p1], li1 = lam[P_DIM + p1];
    unsigned* base =
        (unsigned*)(Bu + ((size_t)b * L_SEQ + (size_t)c * T_CHUNK) * N2);

    // ---------------- phase A: local sums ----------------
    {
        float xr0 = 0, xi0 = 0, xr1 = 0, xi1 = 0;
        for (int j0 = 0; j0 < T_CHUNK; j0 += 8) {
            unsigned R[8], I[8];
            #pragma unroll
            for (int j = 0; j < 8; ++j) {
                R[j] = base[(size_t)(j0 + j) * 512 + t];
                I[j] = base[(size_t)(j0 + j) * 512 + 256 + t];
            }
            #pragma unroll
            for (int j = 0; j < 8; ++j) {
                float nr0 = fmaf(lr0, xr0, fmaf(-li0, xi0, bf_lo(R[j])));
                float ni0 = fmaf(lr0, xi0, fmaf( li0, xr0, bf_lo(I[j])));
                float nr1 = fmaf(lr1, xr1, fmaf(-li1, xi1, bf_hi(R[j])));
                float ni1 = fmaf(lr1, xi1, fmaf( li1, xr1, bf_hi(I[j])));
                xr0 = nr0; xi0 = ni0; xr1 = nr1; xi1 = ni1;
            }
        }
        float* Sb = S + ((size_t)(b * NC + c) * 2) * P_DIM;
        Sb[p0] = xr0; Sb[p1] = xr1;
        Sb[P_DIM + p0] = xi0; Sb[P_DIM + p1] = xi1;
    }

    // ---------------- device-scope barrier over batch b ----------------
    __threadfence();                 // S writes visible device-wide
    __syncthreads();                 // whole block's writes fenced
    if (t == 0) {
        __hip_atomic_fetch_add(&cnt[b], 1, __ATOMIC_ACQ_REL,
                               __HIP_MEMORY_SCOPE_AGENT);
        while (__hip_atomic_load(&cnt[b], __ATOMIC_ACQUIRE,
                                 __HIP_MEMORY_SCOPE_AGENT) < NC)
            __builtin_amdgcn_s_sleep(8);
        __threadfence();
    }
    __syncthreads();

    // ---------------- phase B: carry + apply ----------------
    // P = lam^T_CHUNK via 6 squarings (per p)
    float pr0 = lr0, pi0 = li0, pr1 = lr1, pi1 = li1;
    #pragma unroll
    for (int i = 0; i < 6; ++i) {
        float a0 = pr0 * pr0 - pi0 * pi0, b0 = 2.0f * pr0 * pi0;
        float a1 = pr1 * pr1 - pi1 * pi1, b1 = 2.0f * pr1 * pi1;
        pr0 = a0; pi0 = b0; pr1 = a1; pi1 = b1;
    }

    // preload S[k], k=0..30 (float2: consecutive p0,p1) -- static unroll
    float2 sre[NC - 1], sim[NC - 1];
    #pragma unroll
    for (int k = 0; k < NC - 1; ++k) {
        const float* Sb = S + ((size_t)(b * NC + k) * 2) * P_DIM;
        sre[k] = *(const float2*)&Sb[p0];
        sim[k] = *(const float2*)&Sb[P_DIM + p0];
    }

    // Horner prefix with predicated capture: cin[c]
    float xr0 = 0, xi0 = 0, xr1 = 0, xi1 = 0;
    float cr0 = 0, ci0 = 0, cr1 = 0, ci1 = 0;
    #pragma unroll
    for (int k = 0; k < NC - 1; ++k) {
        if (k == c) { cr0 = xr0; ci0 = xi0; cr1 = xr1; ci1 = xi1; }
        float nr0 = fmaf(pr0, xr0, fmaf(-pi0, xi0, sre[k].x));
        float ni0 = fmaf(pr0, xi0, fmaf( pi0, xr0, sim[k].x));
        float nr1 = fmaf(pr1, xr1, fmaf(-pi1, xi1, sre[k].y));
        float ni1 = fmaf(pr1, xi1, fmaf( pi1, xr1, sim[k].y));
        xr0 = nr0; xi0 = ni0; xr1 = nr1; xi1 = ni1;
    }
    if (c == NC - 1) { cr0 = xr0; ci0 = xi0; cr1 = xr1; ci1 = xi1; }

    // apply chunk scan starting from cin
    xr0 = cr0; xi0 = ci0; xr1 = cr1; xi1 = ci1;
    for (int j0 = 0; j0 < T_CHUNK; j0 += 8) {
        unsigned R[8], I[8];
        #pragma unroll
        for (int j = 0; j < 8; ++j) {
            R[j] = base[(size_t)(j0 + j) * 512 + t];
            I[j] = base[(size_t)(j0 + j) * 512 + 256 + t];
        }
        #pragma unroll
        for (int j = 0; j < 8; ++j) {
            float nr0 = fmaf(lr0, xr0, fmaf(-li0, xi0, bf_lo(R[j])));
            float ni0 = fmaf(lr0, xi0, fmaf( li0, xr0, bf_lo(I[j])));
            float nr1 = fmaf(lr1, xr1, fmaf(-li1, xi1, bf_hi(R[j])));
            float ni1 = fmaf(lr1, xi1, fmaf( li1, xr1, bf_hi(I[j])));
            xr0 = nr0; xi0 = ni0; xr1 = nr1; xi1 = ni1;
            R[j] = f2bf_bits(nr0) | (f2bf_bits(nr1) << 16);
            I[j] = f2bf_bits(ni0) | (f2bf_bits(ni1) << 16);
        }
        #pragma unroll
        for (int j = 0; j < 8; ++j) {
            base[(size_t)(j0 + j) * 512 + t]       = R[j];
            base[(size_t)(j0 + j) * 512 + 256 + t] = I[j];
        }
    }
    if (c == NC - 1) {
        if (interleaved) {
            out_state[((size_t)b * P_DIM + p0) * 2]     = xr0;
            out_state[((size_t)b * P_DIM + p0) * 2 + 1] = xi0;
            out_state[((size_t)b * P_DIM + p1) * 2]     = xr1;
            out_state[((size_t)b * P_DIM + p1) * 2 + 1] = xi1;
        } else {
            out_state[(size_t)b * P_DIM + p0] = xr0;
            out_state[(size_t)b * P_DIM + p1] = xr1;
        }
    }
}

// ---------------------------------------------------------------------------
extern "C" void kernel_launch(void* const* d_in, const int* in_sizes, int n_in,
                              void* d_out, int out_size, void* d_ws, size_t ws_size,
                              hipStream_t stream)
{
    const float* signal   = (const float*)d_in[0];
    // d_in[1] = prev_state: never reaches the scan's b-component -> no effect
    const float* Lre      = (const float*)d_in[2];
    const float* Lim      = (const float*)d_in[3];
    const float* B        = (const float*)d_in[4];
    const float* C        = (const float*)d_in[5];
    const float* Dv       = (const float*)d_in[6];
    const float* log_step = (const float*)d_in[7];

    // ws layout (bytes)
    char* ws = (char*)d_ws;
    unsigned short* sigbf = (unsigned short*)ws;                      // 32 MB
    unsigned short* Bubf  = (unsigned short*)(ws + 33554432);         // 32 MB
    unsigned short* W1bf  = (unsigned short*)(ws + 67108864);         // 2 MB
    unsigned short* W2bf  = (unsigned short*)(ws + 69206016);         // 2 MB
    float*          lam   = (float*)(ws + 71303168);                  // 4 KB
    int*            cnt   = (int*)(ws + 71303168 + 4096);             // 32 B
    float*          S     = (float*)(ws + 71311360);                  // 1 MB
    size_t need = 71835648;
    if (ws_size < need) return;

    float* y_out = (float*)d_out;
    float* state_out = y_out + (size_t)M_DIM * H_DIM;
    int interleaved = (out_size - M_DIM * H_DIM) >= 2 * BATCH_N * P_DIM;

    // prep: convert + build_W + lam + cnt-zero  (one kernel, 20482 blocks)
    prep<<<dim3(NB_CONV + NB_W + 2), dim3(256), 0, stream>>>(
        signal, sigbf, Lre, Lim, log_step, B, C, W1bf, W2bf, lam, cnt);

    // GEMM1: Bu[m][n] = sum_h sig[m][h] * W1[n][h]   (bf16 out)
    gemm_mfma<0><<<dim3(1024), dim3(256), 0, stream>>>(
        sigbf, W1bf, Bubf, H_DIM, nullptr, nullptr);

    // fused scan: sums -> atomic barrier (per batch) -> carry + apply
    scan_fused<<<dim3(BATCH_N, NC), dim3(256), 0, stream>>>(
        Bubf, lam, S, cnt, state_out, interleaved);

    // GEMM2: y[m][h] = sum_k xs[m][k]*W2[h][k] + D[h]*sig[m][h]  (fp32 out)
    gemm_mfma<1><<<dim3(1024), dim3(256), 0, stream>>>(
        Bubf, W2bf, y_out, N2, Dv, sigbf);
}

// Round 9
// 225.932 us; speedup vs baseline: 1.1493x; 1.1493x over previous
//
#include <hip/hip_runtime.h>
#include <math.h>

#define L_SEQ   2048
#define BATCH_N 8
#define H_DIM   1024
#define P_DIM   512
#define M_DIM   (BATCH_N * L_SEQ)   // 16384
#define N2      1024                // packed complex width (re | im)
#define NC      64                  // scan chunks
#define T_CHUNK 32                  // L_SEQ / NC

typedef __attribute__((ext_vector_type(8))) __bf16 bf16x8;
typedef __attribute__((ext_vector_type(4))) float f32x4;

__device__ __forceinline__ unsigned f2bf_bits(float f) {
    unsigned u = __builtin_bit_cast(unsigned, f);
    return (u + 0x7fffu + ((u >> 16) & 1u)) >> 16;   // RNE
}
__device__ __forceinline__ float bf_lo(unsigned v) {
    return __builtin_bit_cast(float, v << 16);
}
__device__ __forceinline__ float bf_hi(unsigned v) {
    return __builtin_bit_cast(float, v & 0xffff0000u);
}
__device__ __forceinline__ float bf2f(unsigned short u) {
    return __builtin_bit_cast(float, (unsigned)u << 16);
}

#define ASYNC_COPY16(gsrc, ldst)                                            \
    __builtin_amdgcn_global_load_lds(                                       \
        (__attribute__((address_space(1))) void*)(gsrc),                    \
        (__attribute__((address_space(3))) void*)(ldst), 16, 0, 0)

// ---------------------------------------------------------------------------
// prep: fused setup_lam + build_W + convert_sig (verified round 7).
//   blocks [0, 16384)        : convert signal f32 -> bf16 (4 elem/thread)
//   blocks [16384, 20480)    : build W1/W2; W1-half recomputes lam inline
//   blocks [20480, 20482)    : write lam_re/lam_im buffer
// lam buffer: [lam_re(512) | lam_im(512)]  (fp32)
// ---------------------------------------------------------------------------
#define NB_CONV 16384
#define NB_W    4096

__global__ __launch_bounds__(256) void prep(
    const float* __restrict__ signal, unsigned short* __restrict__ sigbf,
    const float* __restrict__ Lre_in, const float* __restrict__ Lim_in,
    const float* __restrict__ log_step,
    const float* __restrict__ B, const float* __restrict__ C,
    unsigned short* __restrict__ W1, unsigned short* __restrict__ W2,
    float* __restrict__ lam)
{
    int bid = blockIdx.x;
    if (bid < NB_CONV) {
        size_t i = ((size_t)bid * 256 + threadIdx.x) * 4;
        float4 v = *(const float4*)(signal + i);
        ushort4 o;
        o.x = (unsigned short)f2bf_bits(v.x);
        o.y = (unsigned short)f2bf_bits(v.y);
        o.z = (unsigned short)f2bf_bits(v.z);
        o.w = (unsigned short)f2bf_bits(v.w);
        *(ushort4*)(sigbf + i) = o;
    } else if (bid < NB_CONV + NB_W) {
        int idx = (bid - NB_CONV) * 256 + threadIdx.x;
        if (idx < P_DIM * H_DIM) {                   // W1 half: idx over P*H
            int p = idx >> 10;
            int h = idx & (H_DIM - 1);
            float step = expf(log_step[p]);
            float c = Lre_in[p];
            float d = Lim_in[p];
            float mag = expf(c * step);
            float ang = d * step;
            float lr = mag * cosf(ang);
            float li = mag * sinf(ang);
            float a = lr - 1.0f, bb = li;
            float inv = 1.0f / (c * c + d * d);
            float gre = (a * c + bb * d) * inv;
            float gim = (bb * c - a * d) * inv;
            float bre = B[(size_t)idx * 2];
            float bim = B[(size_t)idx * 2 + 1];
            W1[(size_t)p * H_DIM + h]           = (unsigned short)f2bf_bits(gre * bre - gim * bim);
            W1[(size_t)(P_DIM + p) * H_DIM + h] = (unsigned short)f2bf_bits(gre * bim + gim * bre);
        } else {                                     // W2 half: idx over H*P
            int j = idx - P_DIM * H_DIM;
            int h = j >> 9;
            int p = j & (P_DIM - 1);
            float cre = C[(size_t)j * 2];
            float cim = C[(size_t)j * 2 + 1];
            W2[(size_t)h * N2 + p]         = (unsigned short)f2bf_bits( 2.0f * cre);
            W2[(size_t)h * N2 + P_DIM + p] = (unsigned short)f2bf_bits(-2.0f * cim);
        }
    } else {
        int p = (bid - (NB_CONV + NB_W)) * 256 + threadIdx.x;
        if (p < P_DIM) {
            float step = expf(log_step[p]);
            float c = Lre_in[p];
            float d = Lim_in[p];
            float mag = expf(c * step);
            float ang = d * step;
            lam[p]         = mag * cosf(ang);
            lam[P_DIM + p] = mag * sinf(ang);
        }
    }
}

// ---------------------------------------------------------------------------
// bf16 MFMA GEMM (round-0 verified structure -- best measured: 44 us).
// Out[m][n] = sum_k A[m][k]*W[n][k].
// Block tile 128x128, BK=64, LDS 32 KB, 256 thr = 4 waves 2x2, 4 blocks/CU.
// LDS k-slot swizzle: slot' = (slot + (row>>1)) & 7 via rotated global src.
// NOTE (rounds 1-3 A/B): SQ_LDS_BANK_CONFLICT is a constant 4 cyc per
// ds_read_b128 under ANY swizzle -- structural wave64-b128 cost; don't chase.
// XCD swizzle: XCD x owns m-blocks [16x, 16x+16); 8 n-blocks consecutive.
// MODE 0: bf16 out via LDS-transposed coalesced 16B stores (2 phases).
// MODE 1: f32 out, + D[col]*bf2f(SigBf[row][col]) fused.
// ---------------------------------------------------------------------------
template <int MODE>
__global__ __launch_bounds__(256, 4) void gemm_mfma(
    const unsigned short* __restrict__ A,
    const unsigned short* __restrict__ W,
    void* __restrict__ Out, int K,
    const float* __restrict__ Dvec, const unsigned short* __restrict__ SigBf)
{
    __shared__ unsigned short smem[128 * 64 * 2];   // As 16K | Ws 16K
    unsigned short* As = smem;
    unsigned short* Ws = smem + 128 * 64;

    const int tid  = threadIdx.x;
    const int lane = tid & 63;
    const int wid  = tid >> 6;
    const int wm   = wid >> 1;     // 0..1
    const int wn   = wid & 1;      // 0..1

    // XCD swizzle: 128 m-blocks x 8 n-blocks, XCD x -> m-blocks [16x,16x+16)
    const int id  = blockIdx.x;
    const int xcd = id & 7;
    const int j   = id >> 3;              // 0..127
    const int mb  = xcd * 16 + (j >> 3);  // m-block (128 rows)
    const int nb  = j & 7;                // n-block (128 cols)
    const int m0 = mb * 128;
    const int n0 = nb * 128;

    // --- staging geometry (swizzled) --------------------------------------
    const int srow = tid >> 3;                                  // 0..31
    const int qg   = ((tid & 7) - ((tid >> 4) & 7)) & 7;        // const/lane
    const unsigned short* Abase = A + (size_t)(m0 + srow) * K + qg * 8;
    const unsigned short* Wbase = W + (size_t)(n0 + srow) * K + qg * 8;

    const int fr = lane & 15;        // m-row / n-col within 16
    const int fq = (lane >> 4) & 3;  // k-quad within 32
    const int sw = fr >> 1;          // swizzle rotation for this lane

    f32x4 acc[4][4] = {};

    for (int k0 = 0; k0 < K; k0 += 64) {
        __syncthreads();
        #pragma unroll
        for (int i = 0; i < 4; ++i)      // A: 1024 chunks (128 rows x 8 slots)
            ASYNC_COPY16(Abase + (size_t)(i * 32) * K + k0,
                         As + (size_t)(i * 256 + wid * 64) * 8);
        #pragma unroll
        for (int i = 0; i < 4; ++i)      // W: 1024 chunks
            ASYNC_COPY16(Wbase + (size_t)(i * 32) * K + k0,
                         Ws + (size_t)(i * 256 + wid * 64) * 8);
        __syncthreads();

        #pragma unroll
        for (int kk = 0; kk < 2; ++kk) {
            bf16x8 af[4], wf[4];
            #pragma unroll
            for (int mi = 0; mi < 4; ++mi) {
                int row = wm * 64 + mi * 16 + fr;
                int sl  = (kk * 4 + fq + sw) & 7;
                af[mi] = *(const bf16x8*)&As[(size_t)row * 64 + sl * 8];
            }
            #pragma unroll
            for (int ni = 0; ni < 4; ++ni) {
                int row = wn * 64 + ni * 16 + fr;
                int sl  = (kk * 4 + fq + sw) & 7;
                wf[ni] = *(const bf16x8*)&Ws[(size_t)row * 64 + sl * 8];
            }
            #pragma unroll
            for (int mi = 0; mi < 4; ++mi)
                #pragma unroll
                for (int ni = 0; ni < 4; ++ni)
                    acc[mi][ni] = __builtin_amdgcn_mfma_f32_16x16x32_bf16(
                        af[mi], wf[ni], acc[mi][ni], 0, 0, 0);
        }
    }

    // C/D layout (m89): col = lane&15, row = (lane>>4)*4 + reg
    if (MODE == 0) {
        // bf16 out: transpose through LDS (two 64x128 half-tiles, 16 KB)
        unsigned short* T = smem;
        #pragma unroll
        for (int h = 0; h < 2; ++h) {
            __syncthreads();       // prior LDS readers done
            if (wm == h) {
                #pragma unroll
                for (int mi = 0; mi < 4; ++mi)
                    #pragma unroll
                    for (int ni = 0; ni < 4; ++ni)
                        #pragma unroll
                        for (int r = 0; r < 4; ++r) {
                            int lrow = mi * 16 + fq * 4 + r;      // 0..63
                            int lcol = wn * 64 + ni * 16 + fr;    // 0..127
                            T[lrow * 128 + lcol] =
                                (unsigned short)f2bf_bits(acc[mi][ni][r]);
                        }
            }
            __syncthreads();
            // 64 rows x 128 cols = 1024 chunks of 8 ushorts (16 B)
            #pragma unroll
            for (int jj = 0; jj < 4; ++jj) {
                int chunk = jj * 256 + tid;        // 0..1023
                int row = chunk >> 4;              // 0..63
                int co  = (chunk & 15) * 8;        // 0..120
                *(ulonglong2*)((unsigned short*)Out +
                    (size_t)(m0 + h * 64 + row) * 1024 + n0 + co) =
                    *(const ulonglong2*)&T[row * 128 + co];
            }
        }
    } else {
        float Dl[4];
        #pragma unroll
        for (int ni = 0; ni < 4; ++ni)
            Dl[ni] = Dvec[n0 + wn * 64 + ni * 16 + fr];
        #pragma unroll
        for (int mi = 0; mi < 4; ++mi) {
            #pragma unroll
            for (int ni = 0; ni < 4; ++ni) {
                #pragma unroll
                for (int r = 0; r < 4; ++r) {
                    int row = m0 + wm * 64 + mi * 16 + fq * 4 + r;
                    int col = n0 + wn * 64 + ni * 16 + fr;
                    float v = acc[mi][ni][r];
                    v = fmaf(Dl[ni], bf2f(SigBf[(size_t)row * 1024 + col]), v);
                    ((float*)Out)[(size_t)row * 1024 + col] = v;
                }
            }
        }
    }
}

// ---------------------------------------------------------------------------
// Scan, restructured for latency hiding (round-8 PMC: VALUBusy 5%, HBM 12%,
// occupancy 9.7% -> pure latency-bound with 4-B loads). Total thread count
// is fixed (4 waves/CU), so the fix is bytes-in-flight per lane:
//   - NC=64, T_CHUNK=32; wave = (chunk c, half h) owns 256 channels;
//     lane = 4 channels via uint2 (8 B) loads.
//   - ALL 64 row-loads (512 B/lane) issued upfront into registers
//     (static-indexed arrays; __launch_bounds__(256,1) lifts VGPR cap --
//     occupancy is grid-limited at 1 block/CU, so VGPRs are free).
// S (2 MB) aliases the dead W1 region (free after GEMM1).
// ---------------------------------------------------------------------------
__global__ __launch_bounds__(256, 1) void scan_sums(
    const unsigned short* __restrict__ Bu, const float* __restrict__ lam,
    float* __restrict__ S)
{
    const int b = blockIdx.x, cg = blockIdx.y;
    const int w = threadIdx.x >> 6, l = threadIdx.x & 63;
    const int c    = cg * 2 + (w >> 1);        // 0..63
    const int half = w & 1;
    const int off  = half * 256 + 4 * l;       // channel base (4 channels)
    const int wo   = half * 128 + 2 * l;       // word offset within row

    float lr[4], li[4];
    {
        float4 t0 = *(const float4*)&lam[off];
        float4 t1 = *(const float4*)&lam[P_DIM + off];
        lr[0]=t0.x; lr[1]=t0.y; lr[2]=t0.z; lr[3]=t0.w;
        li[0]=t1.x; li[1]=t1.y; li[2]=t1.z; li[3]=t1.w;
    }

    const unsigned* base =
        (const unsigned*)Bu + ((size_t)b * L_SEQ + (size_t)c * T_CHUNK) * 512;

    uint2 R[T_CHUNK], I[T_CHUNK];
    #pragma unroll
    for (int j = 0; j < T_CHUNK; ++j) {
        R[j] = *(const uint2*)&base[(size_t)j * 512 + wo];
        I[j] = *(const uint2*)&base[(size_t)j * 512 + 256 + wo];
    }
    float xr[4] = {}, xi[4] = {};
    #pragma unroll
    for (int j = 0; j < T_CHUNK; ++j) {
        unsigned rw[2] = {R[j].x, R[j].y};
        unsigned iw[2] = {I[j].x, I[j].y};
        #pragma unroll
        for (int k = 0; k < 2; ++k) {
            int i0 = 2 * k, i1 = 2 * k + 1;
            float nr0 = fmaf(lr[i0], xr[i0], fmaf(-li[i0], xi[i0], bf_lo(rw[k])));
            float ni0 = fmaf(lr[i0], xi[i0], fmaf( li[i0], xr[i0], bf_lo(iw[k])));
            float nr1 = fmaf(lr[i1], xr[i1], fmaf(-li[i1], xi[i1], bf_hi(rw[k])));
            float ni1 = fmaf(lr[i1], xi[i1], fmaf( li[i1], xr[i1], bf_hi(iw[k])));
            xr[i0]=nr0; xi[i0]=ni0; xr[i1]=nr1; xi[i1]=ni1;
        }
    }
    float* Sb = S + ((size_t)(b * NC + c) * 2) * P_DIM;
    *(float4*)&Sb[off]         = make_float4(xr[0], xr[1], xr[2], xr[3]);
    *(float4*)&Sb[P_DIM + off] = make_float4(xi[0], xi[1], xi[2], xi[3]);
}

// scan_apply: streaming-Horner carry (63 steps, batch-8 ping-pong, L2-hot S,
// predicated k<c -- no extra launch), then apply chunk; overwrite Bu (bf16);
// emit state from the c==NC-1 waves.
__global__ __launch_bounds__(256, 1) void scan_apply(
    unsigned short* __restrict__ Bu, const float* __restrict__ lam,
    const float* __restrict__ S, float* __restrict__ out_state,
    int interleaved)
{
    const int b = blockIdx.x, cg = blockIdx.y;
    const int w = threadIdx.x >> 6, l = threadIdx.x & 63;
    const int c    = cg * 2 + (w >> 1);
    const int half = w & 1;
    const int off  = half * 256 + 4 * l;
    const int wo   = half * 128 + 2 * l;

    float lr[4], li[4];
    {
        float4 t0 = *(const float4*)&lam[off];
        float4 t1 = *(const float4*)&lam[P_DIM + off];
        lr[0]=t0.x; lr[1]=t0.y; lr[2]=t0.z; lr[3]=t0.w;
        li[0]=t1.x; li[1]=t1.y; li[2]=t1.z; li[3]=t1.w;
    }

    // P = lam^T_CHUNK (= lam^32) via 5 squarings
    float pr[4], pi[4];
    #pragma unroll
    for (int i = 0; i < 4; ++i) { pr[i] = lr[i]; pi[i] = li[i]; }
    #pragma unroll
    for (int s = 0; s < 5; ++s)
        #pragma unroll
        for (int i = 0; i < 4; ++i) {
            float a  = pr[i] * pr[i] - pi[i] * pi[i];
            float bb = 2.0f * pr[i] * pi[i];
            pr[i] = a; pi[i] = bb;
        }

    const float* Sbase = S + (size_t)b * NC * 2 * P_DIM + off;
    float cr[4] = {}, ci[4] = {};
    float bRA[8][4], bIA[8][4], bRB[8][4], bIB[8][4];

#define LOADB(BR, BI, K0)                                                   \
    _Pragma("unroll")                                                       \
    for (int kk = 0; kk < 8; ++kk) {                                        \
        float4 t0 = *(const float4*)&Sbase[(size_t)((K0) + kk) * 2 * P_DIM];\
        float4 t1 = *(const float4*)&Sbase[(size_t)((K0) + kk) * 2 * P_DIM + P_DIM];\
        BR[kk][0]=t0.x; BR[kk][1]=t0.y; BR[kk][2]=t0.z; BR[kk][3]=t0.w;     \
        BI[kk][0]=t1.x; BI[kk][1]=t1.y; BI[kk][2]=t1.z; BI[kk][3]=t1.w;     \
    }
#define HORN(BR, BI, K0)                                                    \
    _Pragma("unroll")                                                       \
    for (int kk = 0; kk < 8; ++kk) {                                        \
        if ((K0) + kk < c) {                                                \
            _Pragma("unroll")                                               \
            for (int i = 0; i < 4; ++i) {                                   \
                float nr = fmaf(pr[i], cr[i], fmaf(-pi[i], ci[i], BR[kk][i]));\
                float ni = fmaf(pr[i], ci[i], fmaf( pi[i], cr[i], BI[kk][i]));\
                cr[i] = nr; ci[i] = ni;                                     \
            }                                                               \
        }                                                                   \
    }

    LOADB(bRA, bIA, 0)
    #pragma unroll 1
    for (int k0 = 0; k0 < NC; k0 += 16) {
        LOADB(bRB, bIB, k0 + 8)
        HORN(bRA, bIA, k0)
        if (k0 + 16 < NC) { LOADB(bRA, bIA, k0 + 16) }
        HORN(bRB, bIB, k0 + 8)
    }
#undef LOADB
#undef HORN

    // apply chunk scan starting from cin (all row loads issued upfront)
    unsigned* base =
        (unsigned*)Bu + ((size_t)b * L_SEQ + (size_t)c * T_CHUNK) * 512;
    uint2 R[T_CHUNK], I[T_CHUNK];
    #pragma unroll
    for (int j = 0; j < T_CHUNK; ++j) {
        R[j] = *(const uint2*)&base[(size_t)j * 512 + wo];
        I[j] = *(const uint2*)&base[(size_t)j * 512 + 256 + wo];
    }
    float xr[4], xi[4];
    #pragma unroll
    for (int i = 0; i < 4; ++i) { xr[i] = cr[i]; xi[i] = ci[i]; }
    #pragma unroll
    for (int j = 0; j < T_CHUNK; ++j) {
        unsigned rw[2] = {R[j].x, R[j].y};
        unsigned iw[2] = {I[j].x, I[j].y};
        #pragma unroll
        for (int k = 0; k < 2; ++k) {
            int i0 = 2 * k, i1 = 2 * k + 1;
            float nr0 = fmaf(lr[i0], xr[i0], fmaf(-li[i0], xi[i0], bf_lo(rw[k])));
            float ni0 = fmaf(lr[i0], xi[i0], fmaf( li[i0], xr[i0], bf_lo(iw[k])));
            float nr1 = fmaf(lr[i1], xr[i1], fmaf(-li[i1], xi[i1], bf_hi(rw[k])));
            float ni1 = fmaf(lr[i1], xi[i1], fmaf( li[i1], xr[i1], bf_hi(iw[k])));
            xr[i0]=nr0; xi[i0]=ni0; xr[i1]=nr1; xi[i1]=ni1;
            rw[k] = f2bf_bits(nr0) | (f2bf_bits(nr1) << 16);
            iw[k] = f2bf_bits(ni0) | (f2bf_bits(ni1) << 16);
        }
        uint2 ro; ro.x = rw[0]; ro.y = rw[1];
        uint2 io; io.x = iw[0]; io.y = iw[1];
        *(uint2*)&base[(size_t)j * 512 + wo]       = ro;
        *(uint2*)&base[(size_t)j * 512 + 256 + wo] = io;
    }
    if (c == NC - 1) {
        #pragma unroll
        for (int i = 0; i < 4; ++i) {
            int p = off + i;
            if (interleaved) {
                out_state[((size_t)b * P_DIM + p) * 2]     = xr[i];
                out_state[((size_t)b * P_DIM + p) * 2 + 1] = xi[i];
            } else {
                out_state[(size_t)b * P_DIM + p] = xr[i];
            }
        }
    }
}

// ---------------------------------------------------------------------------
extern "C" void kernel_launch(void* const* d_in, const int* in_sizes, int n_in,
                              void* d_out, int out_size, void* d_ws, size_t ws_size,
                              hipStream_t stream)
{
    const float* signal   = (const float*)d_in[0];
    // d_in[1] = prev_state: never reaches the scan's b-component -> no effect
    const float* Lre      = (const float*)d_in[2];
    const float* Lim      = (const float*)d_in[3];
    const float* B        = (const float*)d_in[4];
    const float* C        = (const float*)d_in[5];
    const float* Dv       = (const float*)d_in[6];
    const float* log_step = (const float*)d_in[7];

    // ws layout (bytes)
    char* ws = (char*)d_ws;
    unsigned short* sigbf = (unsigned short*)ws;                      // 32 MB
    unsigned short* Bubf  = (unsigned short*)(ws + 33554432);         // 32 MB
    unsigned short* W1bf  = (unsigned short*)(ws + 67108864);         // 2 MB
    unsigned short* W2bf  = (unsigned short*)(ws + 69206016);         // 2 MB
    float*          lam   = (float*)(ws + 71303168);                  // 4 KB
    // S (8 x 64 x 2 x 512 f32 = 2 MB) ALIASES W1bf: W1 is dead after GEMM1,
    // and scan_sums runs strictly after GEMM1 on the same stream.
    float*          S     = (float*)(ws + 67108864);
    size_t need = 71835648;
    if (ws_size < need) return;

    float* y_out = (float*)d_out;
    float* state_out = y_out + (size_t)M_DIM * H_DIM;
    int interleaved = (out_size - M_DIM * H_DIM) >= 2 * BATCH_N * P_DIM;

    // prep: convert + build_W + lam  (one kernel, 20482 blocks)
    prep<<<dim3(NB_CONV + NB_W + 2), dim3(256), 0, stream>>>(
        signal, sigbf, Lre, Lim, log_step, B, C, W1bf, W2bf, lam);

    // GEMM1: Bu[m][n] = sum_h sig[m][h] * W1[n][h]   (bf16 out)
    gemm_mfma<0><<<dim3(1024), dim3(256), 0, stream>>>(
        sigbf, W1bf, Bubf, H_DIM, nullptr, nullptr);

    // scan: grid (8,32), 4 waves/block; wave = (chunk, channel-half)
    scan_sums<<<dim3(BATCH_N, NC / 2), dim3(256), 0, stream>>>(Bubf, lam, S);
    scan_apply<<<dim3(BATCH_N, NC / 2), dim3(256), 0, stream>>>(
        Bubf, lam, S, state_out, interleaved);

    // GEMM2: y[m][h] = sum_k xs[m][k]*W2[h][k] + D[h]*sig[m][h]  (fp32 out)
    gemm_mfma<1><<<dim3(1024), dim3(256), 0, stream>>>(
        Bubf, W2bf, y_out, N2, Dv, sigbf);
}